// Round 7
// baseline (29.735 us; speedup 1.0000x reference)
//
#include <hip/hip_runtime.h>
#include <float.h>

#define BB 32
#define CC 128
#define HH 64
#define WW 64

// Block = 256 threads = 4 waves = 4 channels; block handles 4 landmarks of one
// (b, channel-group). Grid = 32 b * 32 cg * 2 halves = 2048 blocks, b fastest.
__global__ __launch_bounds__(256) void roipool_kernel(
    const float* __restrict__ x,   // [B,C,64,64]
    const float* __restrict__ lm,  // [B,16]
    float* __restrict__ out)       // [B,C,32,16]
{
    int blk  = blockIdx.x;
    int b    = blk & 31;
    int cg   = (blk >> 5) & 31;
    int half = blk >> 10;          // 0 or 1 -> landmarks 0-3 / 4-7

    int tid = threadIdx.x;
    int wave = tid >> 6;
    int lane = tid & 63;
    int c = cg * 4 + wave;

    __shared__ float s[2][4][8][65];   // double-buffered, padded

    const float* __restrict__ xp = x + (((size_t)b * CC + c) << 12);
    size_t obase_c = ((size_t)b * CC + c) * 32 * 16;

    int i = lane >> 3;   // cell row
    int j = lane & 7;    // cell col

    int buf = 0;
    #pragma unroll
    for (int q = 0; q < 4; ++q) {
        int lmi = half * 4 + q;
        float x0 = lm[b * 16 + 2 * lmi];
        float y0 = lm[b * 16 + 2 * lmi + 1];
        bool visible = (x0 > 0.0f) || (y0 > 0.0f);

        // torchvision column-swap semantics:
        // rois=(b,x1,x2,y1,y2) consumed as (b,start_w,start_h,end_w,end_h)
        int fx = (int)floorf(x0 * 0.25f);
        int fy = (int)floorf(y0 * 0.25f);
        int roi = max(fy - fx + 1, 1);      // roi_w == roi_h
        float bin = (float)roi * 0.125f;    // exact /8

        int orow = 8 * (lmi >> 1) + i;
        int ocol = 8 * (lmi & 1) + j;
        size_t oidx = obase_c + (size_t)orow * 16 + ocol;

        // ---- fast path: roi==1 -> every cell is pixel (fx, fx-7) ----
        if (roi == 1) {                     // block-uniform branch
            int hs = min(max(fx, 0), HH),     he = min(max(fx + 1, 0), HH);
            int ws = min(max(fx - 7, 0), WW), we = min(max(fx - 6, 0), WW);
            bool empty = (he <= hs) || (we <= ws) || !visible;
            float v = 0.0f;
            if (!empty) v = xp[(hs << 6) + ws];
            out[oidx] = empty ? 0.0f : v;
            continue;
        }

        // clipped column window
        int w0 = max(fx - 7, 0);
        int w1 = min(fx - 7 + roi, WW);

        // ---- stage 1: per-column max per row-bin; wave = 1 channel ----
        if (visible && lane >= w0 && lane < w1) {
            #pragma unroll
            for (int t = 0; t < 8; ++t) {
                int hs = min(max((int)floorf((float)t * bin) + fx, 0), HH);
                int he = min(max((int)ceilf((float)(t + 1) * bin) + fx, 0), HH);
                float acc = -FLT_MAX;
                for (int h = hs; h < he; h += 4) {
                    // clamped duplicate rows harmless under max; 4 loads in flight
                    int h1 = min(h + 1, he - 1);
                    int h2 = min(h + 2, he - 1);
                    int h3 = min(h + 3, he - 1);
                    float v0 = xp[(h  << 6) + lane];
                    float v1 = xp[(h1 << 6) + lane];
                    float v2 = xp[(h2 << 6) + lane];
                    float v3 = xp[(h3 << 6) + lane];
                    acc = fmaxf(acc, fmaxf(fmaxf(v0, v1), fmaxf(v2, v3)));
                }
                s[buf][wave][t][lane] = acc;
            }
        }
        __syncthreads();   // single barrier per slow landmark (dbuf covers WAR)

        // ---- stage 2: pool columns from LDS; thread = (ch, i, j) ----
        int hs = min(max((int)floorf((float)i * bin) + fx, 0), HH);
        int he = min(max((int)ceilf((float)(i + 1) * bin) + fx, 0), HH);
        int ws = min(max((int)floorf((float)j * bin) + fx - 7, 0), WW);
        int we = min(max((int)ceilf((float)(j + 1) * bin) + fx - 7, 0), WW);
        bool empty = (he <= hs) || (we <= ws) || !visible;

        float m = -FLT_MAX;
        if (!empty) {
            for (int w = ws; w < we; ++w)   // [ws,we) subset of [w0,w1): written
                m = fmaxf(m, s[buf][wave][i][w]);
        }
        out[oidx] = empty ? 0.0f : m;

        buf ^= 1;
    }
}

extern "C" void kernel_launch(void* const* d_in, const int* in_sizes, int n_in,
                              void* d_out, int out_size, void* d_ws, size_t ws_size,
                              hipStream_t stream) {
    const float* x  = (const float*)d_in[0];
    const float* lm = (const float*)d_in[1];
    float* out = (float*)d_out;

    int blocks = BB * 32 * 2;   // 2048
    roipool_kernel<<<blocks, 256, 0, stream>>>(x, lm, out);
}